// Round 5
// baseline (346.800 us; speedup 1.0000x reference)
//
#include <hip/hip_runtime.h>
#include <hip/hip_bf16.h>

#define B_ 64
#define T_ 2048
#define D_ 512     // K dim of GEMM (KD=QD)
#define A_ 512     // attention dim (N of GEMM)
#define BM 128     // t-rows per block
#define BN 128     // a-cols per block (A split into 4 col-blocks)
#define BK 32      // K step
#define NSTEP (D_/BK)

typedef float f32x4_t __attribute__((ext_vector_type(4)));
typedef short bf16x8_t __attribute__((ext_vector_type(8)));

// ---------------- prep: q = query @ Wq + bq (fp32, exact) ----------------
__global__ void __launch_bounds__(256) qproj_kernel(
    const float* __restrict__ query, const float* __restrict__ Wq,
    const float* __restrict__ bq, float* __restrict__ qbuf) {
  __shared__ float qs[D_];
  const int b = blockIdx.x, tid = threadIdx.x;
  qs[tid] = query[b*D_ + tid];
  qs[tid+256] = query[b*D_ + tid + 256];
  __syncthreads();
  float a0 = bq[tid], a1 = bq[tid+256];
  for (int d = 0; d < D_; ++d) {
    const float qv = qs[d];
    a0 += qv * Wq[d*A_ + tid];
    a1 += qv * Wq[d*A_ + tid + 256];
  }
  qbuf[b*A_ + tid] = a0;
  qbuf[b*A_ + tid+256] = a1;
}

// ---- prep: Wk [D][A] fp32 -> bf16 slab; row (kb,a) = 32 k-values of col a ----
// B-fragment read (frag col a, k-octet lq) = slab + ((kb*512 + a)*64 + lq*16) bytes;
// a full wave's fragment read covers 1 KB contiguous -> perfectly coalesced.
__global__ void __launch_bounds__(256) wkprep_kernel(
    const float* __restrict__ Wk, unsigned int* __restrict__ slab) {
  __shared__ float tile[32][65];
  const int kb = blockIdx.x >> 3;
  const int a0 = (blockIdx.x & 7) * 64;
  const int tid = threadIdx.x;
  for (int p = 0; p < 8; ++p) {
    const int idx = p*256 + tid;
    const int k = idx >> 6, al = idx & 63;
    tile[k][al] = Wk[(kb*32 + k)*A_ + a0 + al];
  }
  __syncthreads();
  const int al = tid >> 2, c = tid & 3;
  const int a = a0 + al;
  union { __hip_bfloat162 h[2]; uint2 u; } w0, w1;
  w0.h[0] = __float22bfloat162_rn(make_float2(tile[c*8+0][al], tile[c*8+1][al]));
  w0.h[1] = __float22bfloat162_rn(make_float2(tile[c*8+2][al], tile[c*8+3][al]));
  w1.h[0] = __float22bfloat162_rn(make_float2(tile[c*8+4][al], tile[c*8+5][al]));
  w1.h[1] = __float22bfloat162_rn(make_float2(tile[c*8+6][al], tile[c*8+7][al]));
  *(uint4*)(slab + (kb*512 + a)*16 + c*4) =
      make_uint4(w0.u.x, w0.u.y, w1.u.x, w1.u.y);
}

// ------- fused energy (partial over 128 cols): no LDS, no barriers, reg-pipelined -------
// Fragment layouts ARE contiguous global reads:
//   A: lane(lq,lr) of frag mf reads keys[row=wm*64+mf*16+lr][k=ks*32+lq*8..+8] (32 B)
//   B: lane(lq,lr) of frag nf reads slab row (ks*512 + a), slot lq (16 B bf16)
__global__ void __launch_bounds__(256, 3) energy_kernel(
    const float* __restrict__ keys, const float* __restrict__ cover,
    const int* __restrict__ key_len, const unsigned char* __restrict__ slab,
    const float* __restrict__ qbuf, const float* __restrict__ Wc,
    const float* __restrict__ Wo, float* __restrict__ epart) {
  __shared__ float redbuf[4][64];

  // XCD-chunk swizzle: dispatch d -> XCD d%8; contiguous logical run per XCD
  // so the 4 col-blocks of one keys-panel share an XCD's L2.
  const int d = blockIdx.x;                  // 0..4095
  const int logical = (d & 7) * 512 + (d >> 3);
  const int ct = logical & 3;                // col-block: cols ct*128..+128
  const int tt = (logical >> 2) & 15;        // t-tile
  const int b  = logical >> 6;

  const int t0 = tt * BM;
  const int kl = key_len[b];
  if (t0 >= kl) return;   // fully-masked tile: energies never read downstream

  const int tid = threadIdx.x;
  const int wid = tid >> 6;
  const int lane = tid & 63;
  const int lq = lane >> 4, lr = lane & 15;
  const int wm = wid >> 1, wn = wid & 1;     // 2x2 waves, 64x64 each

  const float* akeys = keys + ((size_t)b * T_ + t0 + wm*64 + lr) * D_ + lq*8;
  const unsigned char* bsl = slab + (size_t)(ct*BN + wn*64 + lr)*64 + lq*16;

  f32x4_t acc[4][4];
  #pragma unroll
  for (int i = 0; i < 4; ++i)
    #pragma unroll
    for (int j = 0; j < 4; ++j) acc[i][j] = 0.0f;

  // Prefetch buffers: A as raw fp32 (converted at consume so the vm-wait sits
  // next to the MFMAs, not at the pack), B as ready bf16 fragments.
  f32x4_t a0lo[4], a0hi[4], a1lo[4], a1hi[4];
  bf16x8_t b0[4], b1[4];

#define LOAD_STEP(ALO, AHI, BF, KS) do {                                   \
    _Pragma("unroll")                                                      \
    for (int mf = 0; mf < 4; ++mf) {                                       \
      const float* p_ = akeys + mf*16*D_ + (KS)*BK;                        \
      ALO[mf] = *(const f32x4_t*)(p_);                                     \
      AHI[mf] = *(const f32x4_t*)(p_ + 4);                                 \
    }                                                                      \
    _Pragma("unroll")                                                      \
    for (int nf = 0; nf < 4; ++nf)                                         \
      BF[nf] = *(const bf16x8_t*)(bsl + (size_t)(KS)*32768 + nf*1024);     \
  } while (0)

#define MFMA_STEP(ALO, AHI, BF) do {                                       \
    _Pragma("unroll")                                                      \
    for (int mf = 0; mf < 4; ++mf) {                                       \
      union { __hip_bfloat162 h[4]; bf16x8_t v; } pk_;                     \
      pk_.h[0] = __float22bfloat162_rn(make_float2(ALO[mf][0], ALO[mf][1])); \
      pk_.h[1] = __float22bfloat162_rn(make_float2(ALO[mf][2], ALO[mf][3])); \
      pk_.h[2] = __float22bfloat162_rn(make_float2(AHI[mf][0], AHI[mf][1])); \
      pk_.h[3] = __float22bfloat162_rn(make_float2(AHI[mf][2], AHI[mf][3])); \
      _Pragma("unroll")                                                    \
      for (int nf = 0; nf < 4; ++nf)                                       \
        acc[mf][nf] = __builtin_amdgcn_mfma_f32_16x16x32_bf16(             \
            pk_.v, BF[nf], acc[mf][nf], 0, 0, 0);                          \
    }                                                                      \
  } while (0)

  LOAD_STEP(a0lo, a0hi, b0, 0);
  #pragma unroll 1
  for (int ks = 0; ks + 2 < NSTEP; ks += 2) {
    LOAD_STEP(a1lo, a1hi, b1, ks + 1);   // issue next-step loads first
    MFMA_STEP(a0lo, a0hi, b0);           // consume current (vm-wait lands here)
    LOAD_STEP(a0lo, a0hi, b0, ks + 2);
    MFMA_STEP(a1lo, a1hi, b1);
  }
  LOAD_STEP(a1lo, a1hi, b1, NSTEP - 1);
  MFMA_STEP(a0lo, a0hi, b0);
  MFMA_STEP(a1lo, a1hi, b1);

#undef LOAD_STEP
#undef MFMA_STEP

  // epilogue: pre = acc + q[n] + cover[t]*Wc[n]; ep += Wo[n]*tanh(pre)
  float cov[4][4];
  #pragma unroll
  for (int mf = 0; mf < 4; ++mf)
    #pragma unroll
    for (int j = 0; j < 4; ++j)
      cov[mf][j] = cover[(size_t)b*T_ + t0 + wm*64 + mf*16 + lq*4 + j];

  float ep[4][4];
  #pragma unroll
  for (int mf = 0; mf < 4; ++mf)
    #pragma unroll
    for (int j = 0; j < 4; ++j) ep[mf][j] = 0.f;

  #pragma unroll
  for (int nf = 0; nf < 4; ++nf) {
    const int n = ct*BN + wn*64 + nf*16 + lr;
    const float qv = qbuf[b*A_ + n];
    const float wc = Wc[n];
    const float wo = Wo[n];
    #pragma unroll
    for (int mf = 0; mf < 4; ++mf)
      #pragma unroll
      for (int j = 0; j < 4; ++j) {
        float p = acc[mf][nf][j] + qv + cov[mf][j] * wc;
        p = fminf(fmaxf(p, -15.f), 15.f);
        const float t2 = __expf(2.f * p);
        ep[mf][j] += wo * ((t2 - 1.f) * __builtin_amdgcn_rcpf(t2 + 1.f));
      }
  }
  #pragma unroll
  for (int mf = 0; mf < 4; ++mf)
    #pragma unroll
    for (int j = 0; j < 4; ++j) {
      float v = ep[mf][j];
      v += __shfl_xor(v, 1); v += __shfl_xor(v, 2);
      v += __shfl_xor(v, 4); v += __shfl_xor(v, 8);
      ep[mf][j] = v;
    }
  if (lr == 0) {
    #pragma unroll
    for (int mf = 0; mf < 4; ++mf)
      #pragma unroll
      for (int j = 0; j < 4; ++j)
        redbuf[wid][mf*16 + lq*4 + j] = ep[mf][j];
  }
  __syncthreads();
  if (tid < BM) {
    const int wmm = tid >> 6, rl = tid & 63;
    epart[((size_t)ct*B_ + b)*T_ + t0 + tid] = redbuf[wmm*2][rl] + redbuf[wmm*2+1][rl];
  }
}

// ---------------- masked softmax over T (sums 4 col-partials) ----------------
__global__ void __launch_bounds__(1024) softmax_kernel(
    const float* __restrict__ epart, const int* __restrict__ key_len,
    float* __restrict__ attn) {
  __shared__ float sredM[16];
  __shared__ float sredS[16];
  const int b = blockIdx.x, tid = threadIdx.x;
  const int kl = key_len[b];
  float e0 = -3.0e38f, e1 = -3.0e38f;
  if (tid < kl)
    e0 = epart[(size_t)b*T_ + tid] + epart[((size_t)B_ + b)*T_ + tid]
       + epart[((size_t)2*B_ + b)*T_ + tid] + epart[((size_t)3*B_ + b)*T_ + tid];
  if (tid + 1024 < kl)
    e1 = epart[(size_t)b*T_ + tid+1024] + epart[((size_t)B_ + b)*T_ + tid+1024]
       + epart[((size_t)2*B_ + b)*T_ + tid+1024] + epart[((size_t)3*B_ + b)*T_ + tid+1024];
  float m = fmaxf(e0, e1);
  for (int s = 32; s; s >>= 1) m = fmaxf(m, __shfl_xor(m, s));
  if ((tid & 63) == 0) sredM[tid >> 6] = m;
  __syncthreads();
  float M = -3.0e38f;
  #pragma unroll
  for (int i = 0; i < 16; ++i) M = fmaxf(M, sredM[i]);
  const float p0 = (tid < kl) ? __expf(e0 - M) : 0.f;
  const float p1 = (tid + 1024 < kl) ? __expf(e1 - M) : 0.f;
  float s = p0 + p1;
  for (int k = 32; k; k >>= 1) s += __shfl_xor(s, k);
  if ((tid & 63) == 0) sredS[tid >> 6] = s;
  __syncthreads();
  float S = 0.f;
  #pragma unroll
  for (int i = 0; i < 16; ++i) S += sredS[i];
  const float inv = 1.f / S;
  attn[b*T_ + tid] = p0 * inv;
  attn[b*T_ + tid + 1024] = p1 * inv;
}

// ---------------- context: partial sums over t-chunks, then combine ----------------
__global__ void __launch_bounds__(256) ctxpart_kernel(
    const float* __restrict__ value, const float* __restrict__ attn,
    const int* __restrict__ key_len, float* __restrict__ partial) {
  __shared__ float att_s[256];
  const int b = blockIdx.y, ch = blockIdx.x;
  const int tid = threadIdx.x;
  const int kl = key_len[b];
  const int tstart = ch * 256;
  const int tend = min(256, kl - tstart);
  float ax = 0.f, ay = 0.f;
  if (tend > 0) {
    att_s[tid] = attn[b*T_ + tstart + tid];
    __syncthreads();
    const float2* vp = (const float2*)(value + ((size_t)b*T_ + tstart)*D_) + tid;
    #pragma unroll 4
    for (int i = 0; i < tend; ++i) {
      const float w = att_s[i];
      const float2 v = vp[(size_t)i * 256];
      ax += w * v.x; ay += w * v.y;
    }
  }
  float2* pp = (float2*)(partial + (size_t)(b*8 + ch)*D_) + tid;
  *pp = make_float2(ax, ay);
}

__global__ void __launch_bounds__(256) ctxsum_kernel(
    const float* __restrict__ partial, float* __restrict__ ctx) {
  const int b = blockIdx.x, tid = threadIdx.x;
  float sx = 0.f, sy = 0.f;
  #pragma unroll
  for (int c = 0; c < 8; ++c) {
    const float2 v = *((const float2*)(partial + (size_t)(b*8 + c)*D_) + tid);
    sx += v.x; sy += v.y;
  }
  *((float2*)(ctx + (size_t)b*D_) + tid) = make_float2(sx, sy);
}

extern "C" void kernel_launch(void* const* d_in, const int* in_sizes, int n_in,
                              void* d_out, int out_size, void* d_ws, size_t ws_size,
                              hipStream_t stream) {
  const float* query  = (const float*)d_in[0];
  const float* keys   = (const float*)d_in[1];
  const float* value  = (const float*)d_in[2];
  const float* cover  = (const float*)d_in[3];
  const int*   key_len= (const int*)d_in[4];
  const float* Wq     = (const float*)d_in[5];
  const float* bq     = (const float*)d_in[6];
  const float* Wk     = (const float*)d_in[7];
  const float* Wc     = (const float*)d_in[8];
  const float* Wo     = (const float*)d_in[9];

  float* out = (float*)d_out;
  float* ctx_out  = out;            // [64,512]
  float* attn_out = out + B_*A_;    // [64,1,2048]

  float* ws = (float*)d_ws;
  float* qbuf    = ws;                                   // 32768 f32
  float* epart   = ws + 32768;                           // 4*131072 f32
  float* partial = ws + 32768 + 524288;                  // 262144 f32
  unsigned int* slab = (unsigned int*)(ws + 32768 + 524288 + 262144);  // 512 KB

  qproj_kernel<<<B_, 256, 0, stream>>>(query, Wq, bq, qbuf);
  wkprep_kernel<<<128, 256, 0, stream>>>(Wk, slab);
  energy_kernel<<<B_*(T_/BM)*(A_/BN), 256, 0, stream>>>(
      keys, cover, key_len, (const unsigned char*)slab, qbuf, Wc, Wo, epart);
  softmax_kernel<<<B_, 1024, 0, stream>>>(epart, key_len, attn_out);
  ctxpart_kernel<<<dim3(8, B_), 256, 0, stream>>>(value, attn_out, key_len, partial);
  ctxsum_kernel<<<B_, 256, 0, stream>>>(partial, ctx_out);
}

// Round 6
// 239.844 us; speedup vs baseline: 1.4459x; 1.4459x over previous
//
#include <hip/hip_runtime.h>
#include <hip/hip_bf16.h>

#define B_ 64
#define T_ 2048
#define D_ 512     // K dim of GEMM (KD=QD)
#define A_ 512     // attention dim (N of GEMM)
#define BM 128     // t-rows per block
#define BN 128     // a-cols per block (A split into 4 col-blocks)
#define BK 32      // K step
#define NSTEP (D_/BK)

typedef float f32x4_t __attribute__((ext_vector_type(4)));
typedef short bf16x8_t __attribute__((ext_vector_type(8)));

#define GLL16(g, l) __builtin_amdgcn_global_load_lds( \
    (const __attribute__((address_space(1))) void*)(g), \
    (__attribute__((address_space(3))) void*)(l), 16, 0, 0)

// ---------------- prep: q = query @ Wq + bq (fp32, exact) ----------------
__global__ void __launch_bounds__(256) qproj_kernel(
    const float* __restrict__ query, const float* __restrict__ Wq,
    const float* __restrict__ bq, float* __restrict__ qbuf) {
  __shared__ float qs[D_];
  const int b = blockIdx.x, tid = threadIdx.x;
  qs[tid] = query[b*D_ + tid];
  qs[tid+256] = query[b*D_ + tid + 256];
  __syncthreads();
  float a0 = bq[tid], a1 = bq[tid+256];
  for (int d = 0; d < D_; ++d) {
    const float qv = qs[d];
    a0 += qv * Wq[d*A_ + tid];
    a1 += qv * Wq[d*A_ + tid + 256];
  }
  qbuf[b*A_ + tid] = a0;
  qbuf[b*A_ + tid+256] = a1;
}

// ---- prep: Wk [D][A] fp32 -> bf16 slab [kb][a][chunk-swizzled 64B rows] ----
// slab row a of k-block kb holds chunk c (8 bf16) at slot c ^ ((a>>1)&3).
__global__ void __launch_bounds__(256) wkprep_kernel(
    const float* __restrict__ Wk, unsigned int* __restrict__ slab) {
  __shared__ float tile[32][65];
  const int kb = blockIdx.x >> 3;
  const int a0 = (blockIdx.x & 7) * 64;
  const int tid = threadIdx.x;
  for (int p = 0; p < 8; ++p) {
    const int idx = p*256 + tid;
    const int k = idx >> 6, al = idx & 63;
    tile[k][al] = Wk[(kb*32 + k)*A_ + a0 + al];
  }
  __syncthreads();
  const int al = tid >> 2, c = tid & 3;
  const int a = a0 + al;
  union { __hip_bfloat162 h[2]; uint2 u; } w0, w1;
  w0.h[0] = __float22bfloat162_rn(make_float2(tile[c*8+0][al], tile[c*8+1][al]));
  w0.h[1] = __float22bfloat162_rn(make_float2(tile[c*8+2][al], tile[c*8+3][al]));
  w1.h[0] = __float22bfloat162_rn(make_float2(tile[c*8+4][al], tile[c*8+5][al]));
  w1.h[1] = __float22bfloat162_rn(make_float2(tile[c*8+6][al], tile[c*8+7][al]));
  const int cpos = c ^ ((a >> 1) & 3);
  *(uint4*)(slab + (kb*512 + a)*16 + cpos*4) =
      make_uint4(w0.u.x, w0.u.y, w1.u.x, w1.u.y);
}

// ------- fused energy: 3-buffer LDS pipeline, counted vmcnt, 1 lgkm-barrier/step -------
__global__ void __launch_bounds__(256, 3) energy_kernel(
    const float* __restrict__ keys, const float* __restrict__ cover,
    const int* __restrict__ key_len, const unsigned char* __restrict__ slab,
    const float* __restrict__ qbuf, const float* __restrict__ Wc,
    const float* __restrict__ Wo, float* __restrict__ epart) {
  __shared__ __align__(16) unsigned char Abuf[3][BM*64];   // 3 x 8 KB bf16
  __shared__ __align__(16) unsigned char Bbuf[3][BN*64];   // 3 x 8 KB bf16
  __shared__ float redbuf[4][64];

  // XCD-chunk swizzle: dispatch d -> XCD d%8; contiguous logical run per XCD
  // so the 4 col-blocks of one keys-panel share an XCD's L2.
  const int d = blockIdx.x;                  // 0..4095
  const int logical = (d & 7) * 512 + (d >> 3);
  const int ct = logical & 3;                // col-block: cols ct*128..+128
  const int tt = (logical >> 2) & 15;        // t-tile
  const int b  = logical >> 6;

  const int t0 = tt * BM;
  const int kl = key_len[b];
  if (t0 >= kl) return;   // fully-masked tile: energies never read downstream

  const int tid = threadIdx.x;
  const int wid = tid >> 6;
  const int lane = tid & 63;
  const int lq = lane >> 4, lr = lane & 15;
  const int wm = wid >> 1, wn = wid & 1;     // 2x2 waves, 64x64 each

  // ---- A staging role: thread covers row sr = tid>>1, k-half sh = tid&1 (16 fp32)
  const int sr = tid >> 1, sh = tid & 1;
  const float* agp = keys + ((size_t)b*T_ + t0 + sr)*D_ + sh*16;
  const int sx = (sr >> 1) & 3;
  const int sw0 = sr*64 + (((2*sh + 0) ^ sx) << 4);
  const int sw1 = sr*64 + (((2*sh + 1) ^ sx) << 4);

  // ---- B staging: GLL linear copy of pre-swizzled slab rows
  const unsigned char* bsl = slab + ct*8192 + wid*1024 + lane*16;

  f32x4_t acc[4][4];
  #pragma unroll
  for (int i = 0; i < 4; ++i)
    #pragma unroll
    for (int j = 0; j < 4; ++j) acc[i][j] = 0.0f;

  int a_off[4], b_off[4];
  #pragma unroll
  for (int mf = 0; mf < 4; ++mf) {
    const int r = wm*64 + mf*16 + lr;
    a_off[mf] = r*64 + ((lq ^ ((r >> 1) & 3)) << 4);
  }
  #pragma unroll
  for (int nf = 0; nf < 4; ++nf) {
    const int r = wn*64 + nf*16 + lr;
    b_off[nf] = r*64 + ((lq ^ ((r >> 1) & 3)) << 4);
  }

  f32x4_t pA[4];   // in-flight A fp32 (16 floats), consumed same step it's packed
  auto agload = [&](int ksrc) {
    const float* p = agp + ksrc*BK;
    pA[0] = *(const f32x4_t*)(p);
    pA[1] = *(const f32x4_t*)(p + 4);
    pA[2] = *(const f32x4_t*)(p + 8);
    pA[3] = *(const f32x4_t*)(p + 12);
  };
  auto bgll = [&](int ksrc, unsigned char* Bdst) {
    const unsigned char* g = bsl + (size_t)ksrc*32768;
    GLL16(g,        Bdst + wid*1024);
    GLL16(g + 4096, Bdst + 4096 + wid*1024);
  };
  auto apack = [&](unsigned char* Adst) {
    union { __hip_bfloat162 h[2]; uint2 u; } q0, q1;
    q0.h[0] = __float22bfloat162_rn(make_float2(pA[0][0], pA[0][1]));
    q0.h[1] = __float22bfloat162_rn(make_float2(pA[0][2], pA[0][3]));
    q1.h[0] = __float22bfloat162_rn(make_float2(pA[1][0], pA[1][1]));
    q1.h[1] = __float22bfloat162_rn(make_float2(pA[1][2], pA[1][3]));
    *(uint4*)(Adst + sw0) = make_uint4(q0.u.x, q0.u.y, q1.u.x, q1.u.y);
    q0.h[0] = __float22bfloat162_rn(make_float2(pA[2][0], pA[2][1]));
    q0.h[1] = __float22bfloat162_rn(make_float2(pA[2][2], pA[2][3]));
    q1.h[0] = __float22bfloat162_rn(make_float2(pA[3][0], pA[3][1]));
    q1.h[1] = __float22bfloat162_rn(make_float2(pA[3][2], pA[3][3]));
    *(uint4*)(Adst + sw1) = make_uint4(q0.u.x, q0.u.y, q1.u.x, q1.u.y);
  };

  unsigned char *Ar = Abuf[0], *An = Abuf[1], *Aw = Abuf[2];
  unsigned char *Br = Bbuf[0], *Bn = Bbuf[1], *Bw = Bbuf[2];

  // prologue: stage steps 0 and 1 (pack's counted vmcnt keeps GLLs in flight)
  agload(0); bgll(0, Br);
  apack(Ar);
  agload(1); bgll(1, Bn);
  apack(An);
  asm volatile("s_waitcnt lgkmcnt(0)" ::: "memory");
  __builtin_amdgcn_s_barrier();
  __builtin_amdgcn_sched_barrier(0);

  for (int ks = 0; ks < NSTEP; ++ks) {
    const bool pre = (ks + 2 < NSTEP);
    if (pre) {           // issue A-gloads FIRST, then GLLs: pack waits vmcnt(2),
      agload(ks + 2);    // which (in-order) also proves step ks+1's GLLs landed.
      bgll(ks + 2, Bw);
    }
    bf16x8_t aF[4], bF[4];
    #pragma unroll
    for (int mf = 0; mf < 4; ++mf) aF[mf] = *(const bf16x8_t*)(Ar + a_off[mf]);
    #pragma unroll
    for (int nf = 0; nf < 4; ++nf) bF[nf] = *(const bf16x8_t*)(Br + b_off[nf]);
    #pragma unroll
    for (int mf = 0; mf < 4; ++mf)
      #pragma unroll
      for (int nf = 0; nf < 4; ++nf)
        acc[mf][nf] = __builtin_amdgcn_mfma_f32_16x16x32_bf16(aF[mf], bF[nf], acc[mf][nf], 0, 0, 0);
    if (pre) apack(Aw);  // compiler emits counted s_waitcnt vmcnt(2) here
    if (ks + 1 < NSTEP) {
      if (!pre)          // tail: no pack-wait to subsume the GLL completion
        asm volatile("s_waitcnt vmcnt(0)" ::: "memory");
      asm volatile("s_waitcnt lgkmcnt(0)" ::: "memory");
      __builtin_amdgcn_s_barrier();
      __builtin_amdgcn_sched_barrier(0);
    }
    unsigned char* t;
    t = Ar; Ar = An; An = Aw; Aw = t;
    t = Br; Br = Bn; Bn = Bw; Bw = t;
  }

  // epilogue: pre = acc + q[n] + cover[t]*Wc[n]; ep += Wo[n]*tanh(pre)
  float cov[4][4];
  #pragma unroll
  for (int mf = 0; mf < 4; ++mf)
    #pragma unroll
    for (int j = 0; j < 4; ++j)
      cov[mf][j] = cover[(size_t)b*T_ + t0 + wm*64 + mf*16 + lq*4 + j];

  float ep[4][4];
  #pragma unroll
  for (int mf = 0; mf < 4; ++mf)
    #pragma unroll
    for (int j = 0; j < 4; ++j) ep[mf][j] = 0.f;

  #pragma unroll
  for (int nf = 0; nf < 4; ++nf) {
    const int n = ct*BN + wn*64 + nf*16 + lr;
    const float qv = qbuf[b*A_ + n];
    const float wc = Wc[n];
    const float wo = Wo[n];
    #pragma unroll
    for (int mf = 0; mf < 4; ++mf)
      #pragma unroll
      for (int j = 0; j < 4; ++j) {
        float p = acc[mf][nf][j] + qv + cov[mf][j] * wc;
        p = fminf(fmaxf(p, -15.f), 15.f);
        const float t2 = __expf(2.f * p);
        ep[mf][j] += wo * ((t2 - 1.f) * __builtin_amdgcn_rcpf(t2 + 1.f));
      }
  }
  #pragma unroll
  for (int mf = 0; mf < 4; ++mf)
    #pragma unroll
    for (int j = 0; j < 4; ++j) {
      float v = ep[mf][j];
      v += __shfl_xor(v, 1); v += __shfl_xor(v, 2);
      v += __shfl_xor(v, 4); v += __shfl_xor(v, 8);
      ep[mf][j] = v;
    }
  if (lr == 0) {
    #pragma unroll
    for (int mf = 0; mf < 4; ++mf)
      #pragma unroll
      for (int j = 0; j < 4; ++j)
        redbuf[wid][mf*16 + lq*4 + j] = ep[mf][j];
  }
  __syncthreads();
  if (tid < BM) {
    const int wmm = tid >> 6, rl = tid & 63;
    epart[((size_t)ct*B_ + b)*T_ + t0 + tid] = redbuf[wmm*2][rl] + redbuf[wmm*2+1][rl];
  }
}

// ---------------- masked softmax over T (sums 4 col-partials) ----------------
__global__ void __launch_bounds__(1024) softmax_kernel(
    const float* __restrict__ epart, const int* __restrict__ key_len,
    float* __restrict__ attn) {
  __shared__ float sredM[16];
  __shared__ float sredS[16];
  const int b = blockIdx.x, tid = threadIdx.x;
  const int kl = key_len[b];
  float e0 = -3.0e38f, e1 = -3.0e38f;
  if (tid < kl)
    e0 = epart[(size_t)b*T_ + tid] + epart[((size_t)B_ + b)*T_ + tid]
       + epart[((size_t)2*B_ + b)*T_ + tid] + epart[((size_t)3*B_ + b)*T_ + tid];
  if (tid + 1024 < kl)
    e1 = epart[(size_t)b*T_ + tid+1024] + epart[((size_t)B_ + b)*T_ + tid+1024]
       + epart[((size_t)2*B_ + b)*T_ + tid+1024] + epart[((size_t)3*B_ + b)*T_ + tid+1024];
  float m = fmaxf(e0, e1);
  for (int s = 32; s; s >>= 1) m = fmaxf(m, __shfl_xor(m, s));
  if ((tid & 63) == 0) sredM[tid >> 6] = m;
  __syncthreads();
  float M = -3.0e38f;
  #pragma unroll
  for (int i = 0; i < 16; ++i) M = fmaxf(M, sredM[i]);
  const float p0 = (tid < kl) ? __expf(e0 - M) : 0.f;
  const float p1 = (tid + 1024 < kl) ? __expf(e1 - M) : 0.f;
  float s = p0 + p1;
  for (int k = 32; k; k >>= 1) s += __shfl_xor(s, k);
  if ((tid & 63) == 0) sredS[tid >> 6] = s;
  __syncthreads();
  float S = 0.f;
  #pragma unroll
  for (int i = 0; i < 16; ++i) S += sredS[i];
  const float inv = 1.f / S;
  attn[b*T_ + tid] = p0 * inv;
  attn[b*T_ + tid + 1024] = p1 * inv;
}

// ---------------- context: partial sums over t-chunks, then combine ----------------
__global__ void __launch_bounds__(256) ctxpart_kernel(
    const float* __restrict__ value, const float* __restrict__ attn,
    const int* __restrict__ key_len, float* __restrict__ partial) {
  __shared__ float att_s[256];
  const int b = blockIdx.y, ch = blockIdx.x;
  const int tid = threadIdx.x;
  const int kl = key_len[b];
  const int tstart = ch * 256;
  const int tend = min(256, kl - tstart);
  float ax = 0.f, ay = 0.f;
  if (tend > 0) {
    att_s[tid] = attn[b*T_ + tstart + tid];
    __syncthreads();
    const float2* vp = (const float2*)(value + ((size_t)b*T_ + tstart)*D_) + tid;
    #pragma unroll 4
    for (int i = 0; i < tend; ++i) {
      const float w = att_s[i];
      const float2 v = vp[(size_t)i * 256];
      ax += w * v.x; ay += w * v.y;
    }
  }
  float2* pp = (float2*)(partial + (size_t)(b*8 + ch)*D_) + tid;
  *pp = make_float2(ax, ay);
}

__global__ void __launch_bounds__(256) ctxsum_kernel(
    const float* __restrict__ partial, float* __restrict__ ctx) {
  const int b = blockIdx.x, tid = threadIdx.x;
  float sx = 0.f, sy = 0.f;
  #pragma unroll
  for (int c = 0; c < 8; ++c) {
    const float2 v = *((const float2*)(partial + (size_t)(b*8 + c)*D_) + tid);
    sx += v.x; sy += v.y;
  }
  *((float2*)(ctx + (size_t)b*D_) + tid) = make_float2(sx, sy);
}

extern "C" void kernel_launch(void* const* d_in, const int* in_sizes, int n_in,
                              void* d_out, int out_size, void* d_ws, size_t ws_size,
                              hipStream_t stream) {
  const float* query  = (const float*)d_in[0];
  const float* keys   = (const float*)d_in[1];
  const float* value  = (const float*)d_in[2];
  const float* cover  = (const float*)d_in[3];
  const int*   key_len= (const int*)d_in[4];
  const float* Wq     = (const float*)d_in[5];
  const float* bq     = (const float*)d_in[6];
  const float* Wk     = (const float*)d_in[7];
  const float* Wc     = (const float*)d_in[8];
  const float* Wo     = (const float*)d_in[9];

  float* out = (float*)d_out;
  float* ctx_out  = out;            // [64,512]
  float* attn_out = out + B_*A_;    // [64,1,2048]

  float* ws = (float*)d_ws;
  float* qbuf    = ws;                                   // 32768 f32
  float* epart   = ws + 32768;                           // 4*131072 f32
  float* partial = ws + 32768 + 524288;                  // 262144 f32
  unsigned int* slab = (unsigned int*)(ws + 32768 + 524288 + 262144);  // 512 KB

  qproj_kernel<<<B_, 256, 0, stream>>>(query, Wq, bq, qbuf);
  wkprep_kernel<<<128, 256, 0, stream>>>(Wk, slab);
  energy_kernel<<<B_*(T_/BM)*(A_/BN), 256, 0, stream>>>(
      keys, cover, key_len, (const unsigned char*)slab, qbuf, Wc, Wo, epart);
  softmax_kernel<<<B_, 1024, 0, stream>>>(epart, key_len, attn_out);
  ctxpart_kernel<<<dim3(8, B_), 256, 0, stream>>>(value, attn_out, key_len, partial);
  ctxsum_kernel<<<B_, 256, 0, stream>>>(partial, ctx_out);
}